// Round 1
// baseline (680.400 us; speedup 1.0000x reference)
//
#include <hip/hip_runtime.h>

typedef unsigned short u16;
typedef __attribute__((ext_vector_type(8))) __bf16 bf16x8;
typedef __attribute__((ext_vector_type(4))) float f32x4;
typedef __attribute__((ext_vector_type(4))) u16 u16x4;
typedef __attribute__((ext_vector_type(8))) u16 u16x8;

constexpr int S = 2048;
constexpr int H = 2048;
constexpr int NH = 16;
constexpr int HD = 128;
constexpr int M = 4096;   // B*S
constexpr float SCALE = 0.08838834764831845f;  // 1/sqrt(128)

__device__ __forceinline__ u16 f2bf(float f) {
  union { float f; unsigned u; } v; v.f = f;
  unsigned r = v.u + 0x7fffu + ((v.u >> 16) & 1u);  // RNE
  return (u16)(r >> 16);
}
__device__ __forceinline__ float bf2f(u16 u) {
  union { unsigned u; float f; } v; v.u = ((unsigned)u) << 16;
  return v.f;
}

// async global->LDS, 16 bytes per lane. LDS dest must be wave-uniform base + lane*16.
__device__ __forceinline__ void gld16(const u16* g, u16* l) {
  __builtin_amdgcn_global_load_lds(
      (const __attribute__((address_space(1))) void*)g,
      (__attribute__((address_space(3))) void*)l, 16, 0, 0);
}

// ---------------- fp32 -> bf16 cast ----------------
__global__ __launch_bounds__(256) void cast_kernel(const float* __restrict__ in,
                                                   u16* __restrict__ out, int n) {
  int i = (blockIdx.x * 256 + threadIdx.x) * 4;
  if (i >= n) return;
  float4 v = *(const float4*)(in + i);
  u16x4 o;
  o[0] = f2bf(v.x); o[1] = f2bf(v.y); o[2] = f2bf(v.z); o[3] = f2bf(v.w);
  *(u16x4*)(out + i) = o;
}

// ---------------- RoPE cos/sin table: tab[(s*64+d)*2] = cos, +1 = sin ----------------
__global__ __launch_bounds__(256) void rope_table_k(float* __restrict__ tab) {
  int i = blockIdx.x * 256 + threadIdx.x;
  if (i >= S * 64) return;
  int s = i >> 6, d = i & 63;
  float freq = expf(-(float)d * (9.210340371976184f / 64.f));  // 10000^(-d/64)
  float ang = (float)s * freq;
  tab[i * 2]     = cosf(ang);
  tab[i * 2 + 1] = sinf(ang);
}

// ---------------- RoPE apply, in-place on bf16 [M][H] ----------------
__global__ __launch_bounds__(256) void rope_apply_k(u16* X, const float* __restrict__ tab) {
  int i = blockIdx.x * 256 + threadIdx.x;  // [0, M*NH*8)
  int j0 = (i & 7) * 8;                    // d offset within [0,64), 8 elems
  int h  = (i >> 3) & 15;
  int m  = i >> 7;
  int s  = m & (S - 1);
  u16* p = X + (size_t)m * H + h * HD;
  u16x8 lo = *(u16x8*)(p + j0);
  u16x8 hi = *(u16x8*)(p + 64 + j0);
  u16x8 nlo, nhi;
  const float* tb = tab + ((size_t)s * 64 + j0) * 2;
  #pragma unroll
  for (int j = 0; j < 8; ++j) {
    float c = tb[j * 2], sn = tb[j * 2 + 1];
    float xl = bf2f(lo[j]), xh = bf2f(hi[j]);
    nlo[j] = f2bf(xl * c - xh * sn);
    nhi[j] = f2bf(xh * c + xl * sn);
  }
  *(u16x8*)(p + j0) = nlo;
  *(u16x8*)(p + 64 + j0) = nhi;
}

// ---------------- GEMM: C[m,n] = sum_k A[m,k]*W[n,k] + bias[n] ----------------
// m97 structure: 128x128 tile, BK=32, 4 waves each computing 64x64 (4x4 frags).
// OUT_MODE 0: fp32 out [M][H];  1: bf16 out [M][H];  2: bf16 V-transposed [bh][d][s]
template<int OUT_MODE>
__global__ __launch_bounds__(256) void gemm_bt(const u16* __restrict__ A,
                                               const u16* __restrict__ Bw,
                                               const float* __restrict__ bias,
                                               void* __restrict__ Cout) {
  __shared__ u16 As[128 * 32];
  __shared__ u16 Bs[128 * 32];
  const int t = threadIdx.x;
  const int w = t >> 6, l = t & 63;
  const int wr = w >> 1, wc = w & 1;
  const int lr = l & 15, lg = l >> 4;
  const int brow = blockIdx.y * 128, bcol = blockIdx.x * 128;

  f32x4 acc[4][4] = {};

  const int srow = t >> 2;          // 0..63
  const int scol = (t & 3) * 8;     // k element offset of this thread's 16B
  const u16* ga = A  + (size_t)(brow + srow) * H + scol;
  const u16* gb = Bw + (size_t)(bcol + srow) * H + scol;
  u16* la = As + srow * 32 + scol;  // = wave-uniform + lane*16B
  u16* lb = Bs + srow * 32 + scol;

  for (int kt = 0; kt < H; kt += 32) {
    gld16(ga + kt,             la);
    gld16(ga + kt + 64 * H,    la + 64 * 32);
    gld16(gb + kt,             lb);
    gld16(gb + kt + 64 * H,    lb + 64 * 32);
    __syncthreads();  // drains vmcnt -> staged data visible
    bf16x8 af[4], bf[4];
    #pragma unroll
    for (int m = 0; m < 4; ++m)
      af[m] = *(const bf16x8*)(As + (wr * 64 + m * 16 + lr) * 32 + lg * 8);
    #pragma unroll
    for (int n = 0; n < 4; ++n)
      bf[n] = *(const bf16x8*)(Bs + (wc * 64 + n * 16 + lr) * 32 + lg * 8);
    #pragma unroll
    for (int m = 0; m < 4; ++m)
      #pragma unroll
      for (int n = 0; n < 4; ++n)
        acc[m][n] = __builtin_amdgcn_mfma_f32_16x16x32_bf16(af[m], bf[n], acc[m][n], 0, 0, 0);
    __syncthreads();  // all reads done before next stage overwrites
  }

  #pragma unroll
  for (int m = 0; m < 4; ++m) {
    const int row0 = brow + wr * 64 + m * 16 + lg * 4;
    #pragma unroll
    for (int n = 0; n < 4; ++n) {
      const int col = bcol + wc * 64 + n * 16 + lr;
      const float bv = bias[col];
      if constexpr (OUT_MODE == 0) {
        float* C = (float*)Cout;
        #pragma unroll
        for (int r = 0; r < 4; ++r)
          C[(size_t)(row0 + r) * H + col] = acc[m][n][r] + bv;
      } else if constexpr (OUT_MODE == 1) {
        u16* C = (u16*)Cout;
        #pragma unroll
        for (int r = 0; r < 4; ++r)
          C[(size_t)(row0 + r) * H + col] = f2bf(acc[m][n][r] + bv);
      } else {
        // V transposed: Vt[((b*16+h)*128+d)*S + s], 4 consecutive s -> one 8B store
        const int hh = col >> 7, d = col & 127;
        const int b = row0 >> 11, s0 = row0 & (S - 1);
        u16x4 pk;
        #pragma unroll
        for (int r = 0; r < 4; ++r) pk[r] = f2bf(acc[m][n][r] + bv);
        u16* C = (u16*)Cout;
        *(u16x4*)(C + ((size_t)((b * 16 + hh) * 128 + d)) * S + s0) = pk;
      }
    }
  }
}

// ---------------- causal flash attention ----------------
// grid (S/64, B*NH), 256 thr. Wave w owns q rows [qt*64+w*16, +16). KV tile = 64.
// Q/K frags from global (L2-resident), V from pre-transposed Vt, P staged per-wave in LDS.
__global__ __launch_bounds__(256) void attn_fwd(const u16* __restrict__ Q,
                                                const u16* __restrict__ Kx,
                                                const u16* __restrict__ Vt,
                                                u16* __restrict__ O) {
  const int qt = (int)(gridDim.x - 1) - (int)blockIdx.x;  // heavy tiles first
  const int bh = blockIdx.y;
  const int b = bh >> 4, h = bh & 15;
  const int t = threadIdx.x, w = t >> 6, l = t & 63;
  const int lr = l & 15, lg = l >> 4;
  const int q0 = qt * 64 + w * 16;

  __shared__ u16 P_lds[4][16 * 64];
  u16* pw = &P_lds[w][0];

  // Q fragments (A-operand): lane holds Q[q0+lr][k = ks*32 + lg*8 + j]
  bf16x8 qa[4];
  const u16* qbase = Q + (size_t)(b * S + q0 + lr) * H + h * HD;
  #pragma unroll
  for (int ks = 0; ks < 4; ++ks)
    qa[ks] = *(const bf16x8*)(qbase + ks * 32 + lg * 8);

  f32x4 acc[8] = {};
  float mrun[4], lrun[4];
  #pragma unroll
  for (int r = 0; r < 4; ++r) { mrun[r] = -1e30f; lrun[r] = 0.f; }

  const u16* kbase = Kx + (size_t)(b * S) * H + h * HD;
  const u16* vbase = Vt + (size_t)bh * HD * S;

  for (int kt = 0; kt <= qt; ++kt) {
    const int k0 = kt * 64;
    // ---- QK^T: scores[q(16) x key(64)] as 4 col-frags ----
    f32x4 sc[4] = {};
    #pragma unroll
    for (int ks = 0; ks < 4; ++ks) {
      bf16x8 kf[4];
      #pragma unroll
      for (int f = 0; f < 4; ++f)
        kf[f] = *(const bf16x8*)(kbase + (size_t)(k0 + f * 16 + lr) * H + ks * 32 + lg * 8);
      #pragma unroll
      for (int f = 0; f < 4; ++f)
        sc[f] = __builtin_amdgcn_mfma_f32_16x16x32_bf16(qa[ks], kf[f], sc[f], 0, 0, 0);
    }
    // ---- scale + causal mask (only diagonal tile is partial) ----
    const bool diag = (kt == qt);
    float p[4][4];
    #pragma unroll
    for (int f = 0; f < 4; ++f)
      #pragma unroll
      for (int r = 0; r < 4; ++r) {
        float v = sc[f][r] * SCALE;
        if (diag && (f * 16 + lr > w * 16 + lg * 4 + r)) v = -1e30f;
        p[f][r] = v;
      }
    // ---- online softmax (rows live on 16-lane groups) ----
    float resc[4];
    #pragma unroll
    for (int r = 0; r < 4; ++r) {
      float mx = fmaxf(fmaxf(p[0][r], p[1][r]), fmaxf(p[2][r], p[3][r]));
      mx = fmaxf(mx, __shfl_xor(mx, 1));
      mx = fmaxf(mx, __shfl_xor(mx, 2));
      mx = fmaxf(mx, __shfl_xor(mx, 4));
      mx = fmaxf(mx, __shfl_xor(mx, 8));
      float mnew = fmaxf(mrun[r], mx);
      float sum = 0.f;
      #pragma unroll
      for (int f = 0; f < 4; ++f) {
        float e = __expf(p[f][r] - mnew);
        p[f][r] = e;
        sum += e;
      }
      sum += __shfl_xor(sum, 1);
      sum += __shfl_xor(sum, 2);
      sum += __shfl_xor(sum, 4);
      sum += __shfl_xor(sum, 8);
      float rs = __expf(mrun[r] - mnew);
      lrun[r] = lrun[r] * rs + sum;
      mrun[r] = mnew;
      resc[r] = rs;
    }
    #pragma unroll
    for (int fd = 0; fd < 8; ++fd) {
      f32x4 a = acc[fd];
      a[0] *= resc[0]; a[1] *= resc[1]; a[2] *= resc[2]; a[3] *= resc[3];
      acc[fd] = a;
    }
    // ---- P -> LDS (bf16), then PV ----
    #pragma unroll
    for (int f = 0; f < 4; ++f)
      #pragma unroll
      for (int r = 0; r < 4; ++r)
        pw[(lg * 4 + r) * 64 + f * 16 + lr] = f2bf(p[f][r]);
    #pragma unroll
    for (int ks = 0; ks < 2; ++ks) {
      bf16x8 pa = *(const bf16x8*)(pw + lr * 64 + ks * 32 + lg * 8);
      #pragma unroll
      for (int fd = 0; fd < 8; ++fd) {
        bf16x8 vb = *(const bf16x8*)(vbase + (size_t)(fd * 16 + lr) * S + k0 + ks * 32 + lg * 8);
        acc[fd] = __builtin_amdgcn_mfma_f32_16x16x32_bf16(pa, vb, acc[fd], 0, 0, 0);
      }
    }
  }
  // ---- normalize + write bf16 [M][H] ----
  u16* ob = O + (size_t)(b * S + q0 + lg * 4) * H + h * HD;
  #pragma unroll
  for (int r = 0; r < 4; ++r) {
    float inv = 1.f / lrun[r];
    #pragma unroll
    for (int fd = 0; fd < 8; ++fd)
      ob[(size_t)r * H + fd * 16 + lr] = f2bf(acc[fd][r] * inv);
  }
}

// ---------------- launch ----------------
extern "C" void kernel_launch(void* const* d_in, const int* in_sizes, int n_in,
                              void* d_out, int out_size, void* d_ws, size_t ws_size,
                              hipStream_t stream) {
  const float* x  = (const float*)d_in[0];
  const float* wq = (const float*)d_in[1];
  const float* bq = (const float*)d_in[2];
  const float* wk = (const float*)d_in[3];
  const float* bk = (const float*)d_in[4];
  const float* wv = (const float*)d_in[5];
  const float* bv = (const float*)d_in[6];
  const float* wo = (const float*)d_in[7];
  const float* bo = (const float*)d_in[8];

  char* ws = (char*)d_ws;
  u16*   xb  = (u16*)(ws);                       // 16 MiB  [M][H] bf16
  u16*   wqb = (u16*)(ws + (16ull << 20));       //  8 MiB
  u16*   wkb = (u16*)(ws + (24ull << 20));
  u16*   wvb = (u16*)(ws + (32ull << 20));
  u16*   wob = (u16*)(ws + (40ull << 20));
  u16*   Qb  = (u16*)(ws + (48ull << 20));       // 16 MiB
  u16*   Kb  = (u16*)(ws + (64ull << 20));       // 16 MiB
  u16*   Vt  = (u16*)(ws + (80ull << 20));       // 16 MiB [bh][d][s]
  u16*   Ob  = (u16*)(ws + (96ull << 20));       // 16 MiB
  float* tab = (float*)(ws + (112ull << 20));    //  1 MiB cos/sin

  cast_kernel<<<M * H / 1024, 256, 0, stream>>>(x,  xb,  M * H);
  cast_kernel<<<H * H / 1024, 256, 0, stream>>>(wq, wqb, H * H);
  cast_kernel<<<H * H / 1024, 256, 0, stream>>>(wk, wkb, H * H);
  cast_kernel<<<H * H / 1024, 256, 0, stream>>>(wv, wvb, H * H);
  cast_kernel<<<H * H / 1024, 256, 0, stream>>>(wo, wob, H * H);
  rope_table_k<<<(S * 64 + 255) / 256, 256, 0, stream>>>(tab);

  dim3 ggrid(H / 128, M / 128);
  gemm_bt<1><<<ggrid, 256, 0, stream>>>(xb, wqb, bq, Qb);
  gemm_bt<1><<<ggrid, 256, 0, stream>>>(xb, wkb, bk, Kb);
  gemm_bt<2><<<ggrid, 256, 0, stream>>>(xb, wvb, bv, Vt);

  rope_apply_k<<<M * NH * 8 / 256, 256, 0, stream>>>(Qb, tab);
  rope_apply_k<<<M * NH * 8 / 256, 256, 0, stream>>>(Kb, tab);

  attn_fwd<<<dim3(S / 64, 2 * NH), 256, 0, stream>>>(Qb, Kb, Vt, Ob);

  gemm_bt<0><<<ggrid, 256, 0, stream>>>(Ob, wob, bo, (float*)d_out);
}

// Round 2
// 329.578 us; speedup vs baseline: 2.0645x; 2.0645x over previous
//
#include <hip/hip_runtime.h>

typedef unsigned short u16;
typedef __attribute__((ext_vector_type(8))) __bf16 bf16x8;
typedef __attribute__((ext_vector_type(4))) float f32x4;
typedef __attribute__((ext_vector_type(4))) u16 u16x4;
typedef __attribute__((ext_vector_type(8))) u16 u16x8;

constexpr int S = 2048;
constexpr int H = 2048;
constexpr int NH = 16;
constexpr int HD = 128;
constexpr int M = 4096;   // B*S
constexpr float SCALE = 0.08838834764831845f;  // 1/sqrt(128)

__device__ __forceinline__ u16 f2bf(float f) {
  union { float f; unsigned u; } v; v.f = f;
  unsigned r = v.u + 0x7fffu + ((v.u >> 16) & 1u);  // RNE
  return (u16)(r >> 16);
}
__device__ __forceinline__ float bf2f(u16 u) {
  union { unsigned u; float f; } v; v.u = ((unsigned)u) << 16;
  return v.f;
}

// async global->LDS, 16 bytes per lane. LDS dest must be wave-uniform base + lane*16.
__device__ __forceinline__ void gld16(const u16* g, u16* l) {
  __builtin_amdgcn_global_load_lds(
      (const __attribute__((address_space(1))) void*)g,
      (__attribute__((address_space(3))) void*)l, 16, 0, 0);
}

// ---------------- fp32 -> bf16 cast ----------------
__global__ __launch_bounds__(256) void cast_kernel(const float* __restrict__ in,
                                                   u16* __restrict__ out, int n) {
  int i = (blockIdx.x * 256 + threadIdx.x) * 4;
  if (i >= n) return;
  float4 v = *(const float4*)(in + i);
  u16x4 o;
  o[0] = f2bf(v.x); o[1] = f2bf(v.y); o[2] = f2bf(v.z); o[3] = f2bf(v.w);
  *(u16x4*)(out + i) = o;
}

// ---------------- RoPE cos/sin table: tab[(s*64+d)*2] = cos, +1 = sin ----------------
__global__ __launch_bounds__(256) void rope_table_k(float* __restrict__ tab) {
  int i = blockIdx.x * 256 + threadIdx.x;
  if (i >= S * 64) return;
  int s = i >> 6, d = i & 63;
  float freq = expf(-(float)d * (9.210340371976184f / 64.f));  // 10000^(-d/64)
  float ang = (float)s * freq;
  tab[i * 2]     = cosf(ang);
  tab[i * 2 + 1] = sinf(ang);
}

// ---------------- RoPE apply, in-place on bf16 [M][H] ----------------
__global__ __launch_bounds__(256) void rope_apply_k(u16* X, const float* __restrict__ tab) {
  int i = blockIdx.x * 256 + threadIdx.x;  // [0, M*NH*8)
  int j0 = (i & 7) * 8;                    // d offset within [0,64), 8 elems
  int h  = (i >> 3) & 15;
  int m  = i >> 7;
  int s  = m & (S - 1);
  u16* p = X + (size_t)m * H + h * HD;
  u16x8 lo = *(u16x8*)(p + j0);
  u16x8 hi = *(u16x8*)(p + 64 + j0);
  u16x8 nlo, nhi;
  const float* tb = tab + ((size_t)s * 64 + j0) * 2;
  #pragma unroll
  for (int j = 0; j < 8; ++j) {
    float c = tb[j * 2], sn = tb[j * 2 + 1];
    float xl = bf2f(lo[j]), xh = bf2f(hi[j]);
    nlo[j] = f2bf(xl * c - xh * sn);
    nhi[j] = f2bf(xh * c + xl * sn);
  }
  *(u16x8*)(p + j0) = nlo;
  *(u16x8*)(p + 64 + j0) = nhi;
}

// ---------------- GEMM: C[m,n] = sum_k A[m,k]*W[n,k] + bias[n] ----------------
// m97 structure: 128x128 tile, BK=32, 4 waves each computing 64x64 (4x4 frags).
// OUT_MODE 0: fp32 out [M][H];  1: bf16 out [M][H];  2: bf16 V-transposed [bh][d][s]
template<int OUT_MODE>
__global__ __launch_bounds__(256) void gemm_bt(const u16* __restrict__ A,
                                               const u16* __restrict__ Bw,
                                               const float* __restrict__ bias,
                                               void* __restrict__ Cout) {
  __shared__ u16 As[128 * 32];
  __shared__ u16 Bs[128 * 32];
  const int t = threadIdx.x;
  const int w = t >> 6, l = t & 63;
  const int wr = w >> 1, wc = w & 1;
  const int lr = l & 15, lg = l >> 4;
  const int brow = blockIdx.y * 128, bcol = blockIdx.x * 128;

  f32x4 acc[4][4] = {};

  const int srow = t >> 2;          // 0..63
  const int scol = (t & 3) * 8;     // k element offset of this thread's 16B
  const u16* ga = A  + (size_t)(brow + srow) * H + scol;
  const u16* gb = Bw + (size_t)(bcol + srow) * H + scol;
  u16* la = As + srow * 32 + scol;  // = wave-uniform + lane*16B
  u16* lb = Bs + srow * 32 + scol;

  for (int kt = 0; kt < H; kt += 32) {
    gld16(ga + kt,             la);
    gld16(ga + kt + 64 * H,    la + 64 * 32);
    gld16(gb + kt,             lb);
    gld16(gb + kt + 64 * H,    lb + 64 * 32);
    __syncthreads();  // drains vmcnt -> staged data visible
    bf16x8 af[4], bf[4];
    #pragma unroll
    for (int m = 0; m < 4; ++m)
      af[m] = *(const bf16x8*)(As + (wr * 64 + m * 16 + lr) * 32 + lg * 8);
    #pragma unroll
    for (int n = 0; n < 4; ++n)
      bf[n] = *(const bf16x8*)(Bs + (wc * 64 + n * 16 + lr) * 32 + lg * 8);
    #pragma unroll
    for (int m = 0; m < 4; ++m)
      #pragma unroll
      for (int n = 0; n < 4; ++n)
        acc[m][n] = __builtin_amdgcn_mfma_f32_16x16x32_bf16(af[m], bf[n], acc[m][n], 0, 0, 0);
    __syncthreads();  // all reads done before next stage overwrites
  }

  #pragma unroll
  for (int m = 0; m < 4; ++m) {
    const int row0 = brow + wr * 64 + m * 16 + lg * 4;
    #pragma unroll
    for (int n = 0; n < 4; ++n) {
      const int col = bcol + wc * 64 + n * 16 + lr;
      const float bv = bias[col];
      if constexpr (OUT_MODE == 0) {
        float* C = (float*)Cout;
        #pragma unroll
        for (int r = 0; r < 4; ++r)
          C[(size_t)(row0 + r) * H + col] = acc[m][n][r] + bv;
      } else if constexpr (OUT_MODE == 1) {
        u16* C = (u16*)Cout;
        #pragma unroll
        for (int r = 0; r < 4; ++r)
          C[(size_t)(row0 + r) * H + col] = f2bf(acc[m][n][r] + bv);
      } else {
        // V transposed: Vt[((b*16+h)*128+d)*S + s], 4 consecutive s -> one 8B store
        const int hh = col >> 7, d = col & 127;
        const int b = row0 >> 11, s0 = row0 & (S - 1);
        u16x4 pk;
        #pragma unroll
        for (int r = 0; r < 4; ++r) pk[r] = f2bf(acc[m][n][r] + bv);
        u16* C = (u16*)Cout;
        *(u16x4*)(C + ((size_t)((b * 16 + hh) * 128 + d)) * S + s0) = pk;
      }
    }
  }
}

// ---------------- causal flash attention, 2-phase pipelined LDS staging ----------------
// grid (16, B*NH), 256 thr. Block pid handles q-tiles {31-pid, pid} (uniform 33 KV-tile
// visits). KV tile = 64 keys: K staged [64][128], V staged (pre-transposed) [128][64],
// both double-buffered, XOR-swizzled (linear LDS dest + inverse-swizzled global source,
// swizzled ds_read). Stage for kt+1 issued BEFORE compute of kt; single
// __syncthreads per iteration drains vmcnt.
__global__ __launch_bounds__(256) void attn_fwd(const u16* __restrict__ Q,
                                                const u16* __restrict__ Kx,
                                                const u16* __restrict__ Vt,
                                                u16* __restrict__ O) {
  const int pid = blockIdx.x;          // 0..15
  const int bh = blockIdx.y;
  const int b = bh >> 4, h = bh & 15;
  const int t = threadIdx.x, w = t >> 6, l = t & 63;
  const int lr = l & 15, lg = l >> 4;
  const int swz = lr & 7;              // row&7 for all fragment reads (row = f*16+lr)

  __shared__ u16 Ks[2][64 * 128];      // 32 KiB
  __shared__ u16 Vs[2][128 * 64];      // 32 KiB
  __shared__ u16 P_lds[4][16 * 64];    //  8 KiB
  u16* pw = &P_lds[w][0];

  const u16* kbase = Kx + (size_t)(b * S) * H + h * HD;
  const u16* vbase = Vt + (size_t)bh * HD * S;

  // stage K tile [64 rows][16 chunks of 16B]: LDS linear, source chunk j^(row&7)
  auto stageK = [&](int bf, int k0) {
    #pragma unroll
    for (int it = 0; it < 4; ++it) {
      int c = it * 256 + t;
      int row = c >> 4, j = c & 15;
      gld16(kbase + (size_t)(k0 + row) * H + ((j ^ (row & 7)) * 8), &Ks[bf][0] + c * 8);
    }
  };
  // stage V tile [128 rows][8 chunks of 16B]
  auto stageV = [&](int bf, int k0) {
    #pragma unroll
    for (int it = 0; it < 4; ++it) {
      int c = it * 256 + t;
      int row = c >> 3, j = c & 7;
      gld16(vbase + (size_t)row * S + k0 + ((j ^ (row & 7)) * 8), &Vs[bf][0] + c * 8);
    }
  };

  int cur = 0;
  for (int qi = 0; qi < 2; ++qi) {
    const int qt = qi ? pid : (31 - pid);   // heavy tile first
    const int q0 = qt * 64 + w * 16;

    // Q fragments: lane holds Q[q0+lr][ks*32 + lg*8 + j]
    bf16x8 qa[4];
    const u16* qbase = Q + (size_t)(b * S + q0 + lr) * H + h * HD;
    #pragma unroll
    for (int ks = 0; ks < 4; ++ks)
      qa[ks] = *(const bf16x8*)(qbase + ks * 32 + lg * 8);

    f32x4 acc[8] = {};
    float mrun[4], lrun[4];
    #pragma unroll
    for (int r = 0; r < 4; ++r) { mrun[r] = -1e30f; lrun[r] = 0.f; }

    __syncthreads();                 // all waves done reading LDS (prev q-tile)
    stageK(cur, 0);
    stageV(cur, 0);
    __syncthreads();                 // drain vmcnt -> tile 0 visible

    for (int kt = 0; kt <= qt; ++kt) {
      if (kt < qt) {                 // issue next tile BEFORE compute (overlap)
        stageK(cur ^ 1, (kt + 1) * 64);
        stageV(cur ^ 1, (kt + 1) * 64);
      }
      const u16* kl = &Ks[cur][0];
      const u16* vl = &Vs[cur][0];

      // ---- QK^T ----
      f32x4 sc[4] = {};
      #pragma unroll
      for (int ks = 0; ks < 4; ++ks) {
        #pragma unroll
        for (int f = 0; f < 4; ++f) {
          bf16x8 kf = *(const bf16x8*)(kl + (f * 16 + lr) * 128 + (((ks * 4 + lg) ^ swz) * 8));
          sc[f] = __builtin_amdgcn_mfma_f32_16x16x32_bf16(qa[ks], kf, sc[f], 0, 0, 0);
        }
      }
      // ---- scale + causal mask (only diagonal tile is partial) ----
      const bool diag = (kt == qt);
      float p[4][4];
      #pragma unroll
      for (int f = 0; f < 4; ++f)
        #pragma unroll
        for (int r = 0; r < 4; ++r) {
          float v = sc[f][r] * SCALE;
          if (diag && (f * 16 + lr > w * 16 + lg * 4 + r)) v = -1e30f;
          p[f][r] = v;
        }
      // ---- online softmax (rows live on 16-lane groups) ----
      float resc[4];
      #pragma unroll
      for (int r = 0; r < 4; ++r) {
        float mx = fmaxf(fmaxf(p[0][r], p[1][r]), fmaxf(p[2][r], p[3][r]));
        mx = fmaxf(mx, __shfl_xor(mx, 1));
        mx = fmaxf(mx, __shfl_xor(mx, 2));
        mx = fmaxf(mx, __shfl_xor(mx, 4));
        mx = fmaxf(mx, __shfl_xor(mx, 8));
        float mnew = fmaxf(mrun[r], mx);
        float sum = 0.f;
        #pragma unroll
        for (int f = 0; f < 4; ++f) {
          float e = __expf(p[f][r] - mnew);
          p[f][r] = e;
          sum += e;
        }
        sum += __shfl_xor(sum, 1);
        sum += __shfl_xor(sum, 2);
        sum += __shfl_xor(sum, 4);
        sum += __shfl_xor(sum, 8);
        float rs = __expf(mrun[r] - mnew);
        lrun[r] = lrun[r] * rs + sum;
        mrun[r] = mnew;
        resc[r] = rs;
      }
      #pragma unroll
      for (int fd = 0; fd < 8; ++fd) {
        f32x4 a = acc[fd];
        a[0] *= resc[0]; a[1] *= resc[1]; a[2] *= resc[2]; a[3] *= resc[3];
        acc[fd] = a;
      }
      // ---- P -> LDS (bf16, XOR-swizzled both sides), then PV ----
      #pragma unroll
      for (int f = 0; f < 4; ++f)
        #pragma unroll
        for (int r = 0; r < 4; ++r) {
          int row = lg * 4 + r, col = f * 16 + lr;
          pw[row * 64 + (col ^ ((row & 7) << 3))] = f2bf(p[f][r]);
        }
      #pragma unroll
      for (int ks = 0; ks < 2; ++ks) {
        int col0 = ks * 32 + lg * 8;
        bf16x8 pa = *(const bf16x8*)(pw + lr * 64 + (col0 ^ (swz << 3)));
        #pragma unroll
        for (int fd = 0; fd < 8; ++fd) {
          bf16x8 vb = *(const bf16x8*)(vl + (fd * 16 + lr) * 64 + (((ks * 4 + lg) ^ swz) * 8));
          acc[fd] = __builtin_amdgcn_mfma_f32_16x16x32_bf16(pa, vb, acc[fd], 0, 0, 0);
        }
      }
      __syncthreads();               // next tile staged AND this buffer free
      cur ^= 1;
    }

    // ---- normalize + write bf16 [M][H] ----
    u16* ob = O + (size_t)(b * S + q0 + lg * 4) * H + h * HD;
    #pragma unroll
    for (int r = 0; r < 4; ++r) {
      float inv = 1.f / lrun[r];
      #pragma unroll
      for (int fd = 0; fd < 8; ++fd)
        ob[(size_t)r * H + fd * 16 + lr] = f2bf(acc[fd][r] * inv);
    }
  }
}

// ---------------- launch ----------------
extern "C" void kernel_launch(void* const* d_in, const int* in_sizes, int n_in,
                              void* d_out, int out_size, void* d_ws, size_t ws_size,
                              hipStream_t stream) {
  const float* x  = (const float*)d_in[0];
  const float* wq = (const float*)d_in[1];
  const float* bq = (const float*)d_in[2];
  const float* wk = (const float*)d_in[3];
  const float* bk = (const float*)d_in[4];
  const float* wv = (const float*)d_in[5];
  const float* bv = (const float*)d_in[6];
  const float* wo = (const float*)d_in[7];
  const float* bo = (const float*)d_in[8];

  char* ws = (char*)d_ws;
  u16*   xb  = (u16*)(ws);                       // 16 MiB  [M][H] bf16
  u16*   wqb = (u16*)(ws + (16ull << 20));       //  8 MiB
  u16*   wkb = (u16*)(ws + (24ull << 20));
  u16*   wvb = (u16*)(ws + (32ull << 20));
  u16*   wob = (u16*)(ws + (40ull << 20));
  u16*   Qb  = (u16*)(ws + (48ull << 20));       // 16 MiB
  u16*   Kb  = (u16*)(ws + (64ull << 20));       // 16 MiB
  u16*   Vt  = (u16*)(ws + (80ull << 20));       // 16 MiB [bh][d][s]
  u16*   Ob  = (u16*)(ws + (96ull << 20));       // 16 MiB
  float* tab = (float*)(ws + (112ull << 20));    //  1 MiB cos/sin

  cast_kernel<<<M * H / 1024, 256, 0, stream>>>(x,  xb,  M * H);
  cast_kernel<<<H * H / 1024, 256, 0, stream>>>(wq, wqb, H * H);
  cast_kernel<<<H * H / 1024, 256, 0, stream>>>(wk, wkb, H * H);
  cast_kernel<<<H * H / 1024, 256, 0, stream>>>(wv, wvb, H * H);
  cast_kernel<<<H * H / 1024, 256, 0, stream>>>(wo, wob, H * H);
  rope_table_k<<<(S * 64 + 255) / 256, 256, 0, stream>>>(tab);

  dim3 ggrid(H / 128, M / 128);
  gemm_bt<1><<<ggrid, 256, 0, stream>>>(xb, wqb, bq, Qb);
  gemm_bt<1><<<ggrid, 256, 0, stream>>>(xb, wkb, bk, Kb);
  gemm_bt<2><<<ggrid, 256, 0, stream>>>(xb, wvb, bv, Vt);

  rope_apply_k<<<M * NH * 8 / 256, 256, 0, stream>>>(Qb, tab);
  rope_apply_k<<<M * NH * 8 / 256, 256, 0, stream>>>(Kb, tab);

  attn_fwd<<<dim3(16, 2 * NH), 256, 0, stream>>>(Qb, Kb, Vt, Ob);

  gemm_bt<0><<<ggrid, 256, 0, stream>>>(Ob, wob, bo, (float*)d_out);
}

// Round 3
// 314.922 us; speedup vs baseline: 2.1605x; 1.0465x over previous
//
#include <hip/hip_runtime.h>

typedef unsigned short u16;
typedef __attribute__((ext_vector_type(8))) __bf16 bf16x8;
typedef __attribute__((ext_vector_type(4))) float f32x4;
typedef __attribute__((ext_vector_type(4))) u16 u16x4;
typedef __attribute__((ext_vector_type(8))) u16 u16x8;

constexpr int S = 2048;
constexpr int H = 2048;
constexpr int NH = 16;
constexpr int HD = 128;
constexpr int M = 4096;   // B*S
constexpr float SCALE = 0.08838834764831845f;  // 1/sqrt(128)

__device__ __forceinline__ u16 f2bf(float f) {
  union { float f; unsigned u; } v; v.f = f;
  unsigned r = v.u + 0x7fffu + ((v.u >> 16) & 1u);  // RNE
  return (u16)(r >> 16);
}
__device__ __forceinline__ float bf2f(u16 u) {
  union { unsigned u; float f; } v; v.u = ((unsigned)u) << 16;
  return v.f;
}
__device__ __forceinline__ unsigned cvt_pk_bf16(float lo, float hi) {
  unsigned r;
  asm("v_cvt_pk_bf16_f32 %0, %1, %2" : "=v"(r) : "v"(lo), "v"(hi));
  return r;
}

// async global->LDS, 16 bytes per lane. LDS dest must be wave-uniform base + lane*16.
__device__ __forceinline__ void gld16(const u16* g, u16* l) {
  __builtin_amdgcn_global_load_lds(
      (const __attribute__((address_space(1))) void*)g,
      (__attribute__((address_space(3))) void*)l, 16, 0, 0);
}

// ---------------- fp32 -> bf16 cast (x) ----------------
__global__ __launch_bounds__(256) void cast_kernel(const float* __restrict__ in,
                                                   u16* __restrict__ out, int n) {
  int i = (blockIdx.x * 256 + threadIdx.x) * 4;
  if (i >= n) return;
  float4 v = *(const float4*)(in + i);
  u16x4 o;
  o[0] = f2bf(v.x); o[1] = f2bf(v.y); o[2] = f2bf(v.z); o[3] = f2bf(v.w);
  *(u16x4*)(out + i) = o;
}

// ---------------- 4 weight casts in one dispatch (blockIdx.y selects) ----------------
__global__ __launch_bounds__(256) void cast4_kernel(const float* __restrict__ i0,
                                                    const float* __restrict__ i1,
                                                    const float* __restrict__ i2,
                                                    const float* __restrict__ i3,
                                                    u16* o0, u16* o1, u16* o2, u16* o3) {
  const float* in; u16* out;
  switch (blockIdx.y) {
    case 0: in = i0; out = o0; break;
    case 1: in = i1; out = o1; break;
    case 2: in = i2; out = o2; break;
    default: in = i3; out = o3; break;
  }
  int i = (blockIdx.x * 256 + threadIdx.x) * 4;
  float4 v = *(const float4*)(in + i);
  u16x4 o;
  o[0] = f2bf(v.x); o[1] = f2bf(v.y); o[2] = f2bf(v.z); o[3] = f2bf(v.w);
  *(u16x4*)(out + i) = o;
}

// ---------------- RoPE cos/sin table: tab[(s*64+d)*2] = cos, +1 = sin ----------------
__global__ __launch_bounds__(256) void rope_table_k(float* __restrict__ tab) {
  int i = blockIdx.x * 256 + threadIdx.x;
  if (i >= S * 64) return;
  int s = i >> 6, d = i & 63;
  float freq = expf(-(float)d * (9.210340371976184f / 64.f));  // 10000^(-d/64)
  float ang = (float)s * freq;
  tab[i * 2]     = cosf(ang);
  tab[i * 2 + 1] = sinf(ang);
}

// ---------------- RoPE apply to Q (pre-scaled by 1/sqrt(hd)) and K, one dispatch ----------------
__global__ __launch_bounds__(256) void rope_apply2_k(u16* __restrict__ Qb, u16* __restrict__ Kb,
                                                     const float* __restrict__ tab) {
  u16* X = blockIdx.y ? Kb : Qb;
  const float sc = blockIdx.y ? 1.f : SCALE;
  int i = blockIdx.x * 256 + threadIdx.x;  // [0, M*NH*8)
  int j0 = (i & 7) * 8;                    // d offset within [0,64), 8 elems
  int h  = (i >> 3) & 15;
  int m  = i >> 7;
  int s  = m & (S - 1);
  u16* p = X + (size_t)m * H + h * HD;
  u16x8 lo = *(u16x8*)(p + j0);
  u16x8 hi = *(u16x8*)(p + 64 + j0);
  u16x8 nlo, nhi;
  const float* tb = tab + ((size_t)s * 64 + j0) * 2;
  #pragma unroll
  for (int j = 0; j < 8; ++j) {
    float c = tb[j * 2], sn = tb[j * 2 + 1];
    float xl = bf2f(lo[j]), xh = bf2f(hi[j]);
    nlo[j] = f2bf((xl * c - xh * sn) * sc);
    nhi[j] = f2bf((xh * c + xl * sn) * sc);
  }
  *(u16x8*)(p + j0) = nlo;
  *(u16x8*)(p + 64 + j0) = nhi;
}

// ---------------- shared GEMM body pieces (m97 structure) ----------------
// C[m,n] = sum_k A[m,k]*W[n,k] (+bias). 128x128 tile, BK=32, 4 waves of 64x64.

// ---------------- fused QKV GEMM: blockIdx.z selects weight/bias/output ----------------
__global__ __launch_bounds__(256) void gemm_qkv(const u16* __restrict__ A,
                                                const u16* __restrict__ Wq,
                                                const u16* __restrict__ Wk,
                                                const u16* __restrict__ Wv,
                                                const float* __restrict__ bq,
                                                const float* __restrict__ bk,
                                                const float* __restrict__ bv,
                                                u16* __restrict__ Qb,
                                                u16* __restrict__ Kb,
                                                u16* __restrict__ Vt) {
  __shared__ u16 As[128 * 32];
  __shared__ u16 Bs[128 * 32];
  const int z = blockIdx.z;
  const u16* Bw = (z == 0) ? Wq : (z == 1) ? Wk : Wv;
  const float* bias = (z == 0) ? bq : (z == 1) ? bk : bv;
  const int t = threadIdx.x;
  const int w = t >> 6, l = t & 63;
  const int wr = w >> 1, wc = w & 1;
  const int lr = l & 15, lg = l >> 4;
  const int brow = blockIdx.y * 128, bcol = blockIdx.x * 128;

  f32x4 acc[4][4] = {};

  const int srow = t >> 2;
  const int scol = (t & 3) * 8;
  const u16* ga = A  + (size_t)(brow + srow) * H + scol;
  const u16* gb = Bw + (size_t)(bcol + srow) * H + scol;
  u16* la = As + srow * 32 + scol;
  u16* lb = Bs + srow * 32 + scol;

  for (int kt = 0; kt < H; kt += 32) {
    gld16(ga + kt,          la);
    gld16(ga + kt + 64 * H, la + 64 * 32);
    gld16(gb + kt,          lb);
    gld16(gb + kt + 64 * H, lb + 64 * 32);
    __syncthreads();
    bf16x8 af[4], bf[4];
    #pragma unroll
    for (int m = 0; m < 4; ++m)
      af[m] = *(const bf16x8*)(As + (wr * 64 + m * 16 + lr) * 32 + lg * 8);
    #pragma unroll
    for (int n = 0; n < 4; ++n)
      bf[n] = *(const bf16x8*)(Bs + (wc * 64 + n * 16 + lr) * 32 + lg * 8);
    #pragma unroll
    for (int m = 0; m < 4; ++m)
      #pragma unroll
      for (int n = 0; n < 4; ++n)
        acc[m][n] = __builtin_amdgcn_mfma_f32_16x16x32_bf16(af[m], bf[n], acc[m][n], 0, 0, 0);
    __syncthreads();
  }

  #pragma unroll
  for (int m = 0; m < 4; ++m) {
    const int row0 = brow + wr * 64 + m * 16 + lg * 4;
    #pragma unroll
    for (int n = 0; n < 4; ++n) {
      const int col = bcol + wc * 64 + n * 16 + lr;
      const float bv2 = bias[col];
      if (z < 2) {
        u16* C = z ? Kb : Qb;
        #pragma unroll
        for (int r = 0; r < 4; ++r)
          C[(size_t)(row0 + r) * H + col] = f2bf(acc[m][n][r] + bv2);
      } else {
        // V transposed: Vt[((b*16+h)*128+d)*S + s], 4 consecutive s -> one 8B store
        const int hh = col >> 7, d = col & 127;
        const int b = row0 >> 11, s0 = row0 & (S - 1);
        u16x4 pk;
        #pragma unroll
        for (int r = 0; r < 4; ++r) pk[r] = f2bf(acc[m][n][r] + bv2);
        *(u16x4*)(Vt + ((size_t)((b * 16 + hh) * 128 + d)) * S + s0) = pk;
      }
    }
  }
}

// ---------------- output GEMM (fp32 out) ----------------
__global__ __launch_bounds__(256) void gemm_out(const u16* __restrict__ A,
                                                const u16* __restrict__ Bw,
                                                const float* __restrict__ bias,
                                                float* __restrict__ Cout) {
  __shared__ u16 As[128 * 32];
  __shared__ u16 Bs[128 * 32];
  const int t = threadIdx.x;
  const int w = t >> 6, l = t & 63;
  const int wr = w >> 1, wc = w & 1;
  const int lr = l & 15, lg = l >> 4;
  const int brow = blockIdx.y * 128, bcol = blockIdx.x * 128;

  f32x4 acc[4][4] = {};

  const int srow = t >> 2;
  const int scol = (t & 3) * 8;
  const u16* ga = A  + (size_t)(brow + srow) * H + scol;
  const u16* gb = Bw + (size_t)(bcol + srow) * H + scol;
  u16* la = As + srow * 32 + scol;
  u16* lb = Bs + srow * 32 + scol;

  for (int kt = 0; kt < H; kt += 32) {
    gld16(ga + kt,          la);
    gld16(ga + kt + 64 * H, la + 64 * 32);
    gld16(gb + kt,          lb);
    gld16(gb + kt + 64 * H, lb + 64 * 32);
    __syncthreads();
    bf16x8 af[4], bf[4];
    #pragma unroll
    for (int m = 0; m < 4; ++m)
      af[m] = *(const bf16x8*)(As + (wr * 64 + m * 16 + lr) * 32 + lg * 8);
    #pragma unroll
    for (int n = 0; n < 4; ++n)
      bf[n] = *(const bf16x8*)(Bs + (wc * 64 + n * 16 + lr) * 32 + lg * 8);
    #pragma unroll
    for (int m = 0; m < 4; ++m)
      #pragma unroll
      for (int n = 0; n < 4; ++n)
        acc[m][n] = __builtin_amdgcn_mfma_f32_16x16x32_bf16(af[m], bf[n], acc[m][n], 0, 0, 0);
    __syncthreads();
  }

  #pragma unroll
  for (int m = 0; m < 4; ++m) {
    const int row0 = brow + wr * 64 + m * 16 + lg * 4;
    #pragma unroll
    for (int n = 0; n < 4; ++n) {
      const int col = bcol + wc * 64 + n * 16 + lr;
      const float bv2 = bias[col];
      #pragma unroll
      for (int r = 0; r < 4; ++r)
        Cout[(size_t)(row0 + r) * H + col] = acc[m][n][r] + bv2;
    }
  }
}

// ---------------- causal flash attention, 2-phase pipelined LDS staging ----------------
// grid 512 blocks. XCD-aware decode: all 16 blocks of a head land on the same XCD
// (bh%8 == id%8), so the per-XCD L2 working set is 4 heads' K+V = 4 MB (fits L2).
// Block handles q-tiles {31-pid, pid} (uniform 33 KV-tile visits). KV tile = 64:
// K staged [64][128], V staged (pre-transposed) [128][64], double-buffered,
// XOR-swizzled (linear LDS dest + inverse-swizzled global source, swizzled ds_read).
__global__ __launch_bounds__(256) void attn_fwd(const u16* __restrict__ Q,
                                                const u16* __restrict__ Kx,
                                                const u16* __restrict__ Vt,
                                                u16* __restrict__ O) {
  const int id = blockIdx.x;
  const int xcd = id & 7, slot = id >> 3;
  const int bh = (slot >> 4) * 8 + xcd;    // 0..31
  const int pid = slot & 15;               // 0..15
  const int b = bh >> 4, h = bh & 15;
  const int t = threadIdx.x, w = t >> 6, l = t & 63;
  const int lr = l & 15, lg = l >> 4;
  const int swz = lr & 7;

  __shared__ u16 Ks[2][64 * 128];      // 32 KiB
  __shared__ u16 Vs[2][128 * 64];      // 32 KiB
  __shared__ u16 P_lds[4][16 * 64];    //  8 KiB
  u16* pw = &P_lds[w][0];

  const u16* kbase = Kx + (size_t)(b * S) * H + h * HD;
  const u16* vbase = Vt + (size_t)bh * HD * S;

  auto stageK = [&](int bf, int k0) {
    #pragma unroll
    for (int it = 0; it < 4; ++it) {
      int c = it * 256 + t;
      int row = c >> 4, j = c & 15;
      gld16(kbase + (size_t)(k0 + row) * H + ((j ^ (row & 7)) * 8), &Ks[bf][0] + c * 8);
    }
  };
  auto stageV = [&](int bf, int k0) {
    #pragma unroll
    for (int it = 0; it < 4; ++it) {
      int c = it * 256 + t;
      int row = c >> 3, j = c & 7;
      gld16(vbase + (size_t)row * S + k0 + ((j ^ (row & 7)) * 8), &Vs[bf][0] + c * 8);
    }
  };

  int cur = 0;
  for (int qi = 0; qi < 2; ++qi) {
    const int qt = qi ? pid : (31 - pid);   // heavy tile first
    const int q0 = qt * 64 + w * 16;

    // Q fragments (already RoPE'd and pre-scaled by 1/sqrt(hd))
    bf16x8 qa[4];
    const u16* qbase = Q + (size_t)(b * S + q0 + lr) * H + h * HD;
    #pragma unroll
    for (int ks = 0; ks < 4; ++ks)
      qa[ks] = *(const bf16x8*)(qbase + ks * 32 + lg * 8);

    f32x4 acc[8] = {};
    float mrun[4], lrun[4];
    #pragma unroll
    for (int r = 0; r < 4; ++r) { mrun[r] = -1e30f; lrun[r] = 0.f; }

    __syncthreads();
    stageK(cur, 0);
    stageV(cur, 0);
    __syncthreads();

    for (int kt = 0; kt <= qt; ++kt) {
      if (kt < qt) {                 // issue next tile BEFORE compute (overlap)
        stageK(cur ^ 1, (kt + 1) * 64);
        stageV(cur ^ 1, (kt + 1) * 64);
      }
      const u16* kl = &Ks[cur][0];
      const u16* vl = &Vs[cur][0];

      // ---- QK^T ----
      f32x4 sc[4] = {};
      __builtin_amdgcn_s_setprio(1);
      #pragma unroll
      for (int ks = 0; ks < 4; ++ks) {
        #pragma unroll
        for (int f = 0; f < 4; ++f) {
          bf16x8 kf = *(const bf16x8*)(kl + (f * 16 + lr) * 128 + (((ks * 4 + lg) ^ swz) * 8));
          sc[f] = __builtin_amdgcn_mfma_f32_16x16x32_bf16(qa[ks], kf, sc[f], 0, 0, 0);
        }
      }
      __builtin_amdgcn_s_setprio(0);
      // ---- causal mask (Q pre-scaled; only diagonal tile is partial) ----
      const bool diag = (kt == qt);
      float p[4][4];
      #pragma unroll
      for (int f = 0; f < 4; ++f)
        #pragma unroll
        for (int r = 0; r < 4; ++r) {
          float v = sc[f][r];
          if (diag && (f * 16 + lr > w * 16 + lg * 4 + r)) v = -1e30f;
          p[f][r] = v;
        }
      // ---- online softmax with defer-max (T13, THR=8) ----
      float mx[4];
      #pragma unroll
      for (int r = 0; r < 4; ++r) {
        float m0 = fmaxf(fmaxf(p[0][r], p[1][r]), fmaxf(p[2][r], p[3][r]));
        m0 = fmaxf(m0, __shfl_xor(m0, 1));
        m0 = fmaxf(m0, __shfl_xor(m0, 2));
        m0 = fmaxf(m0, __shfl_xor(m0, 4));
        m0 = fmaxf(m0, __shfl_xor(m0, 8));
        mx[r] = m0;
      }
      bool grow = (mx[0] > mrun[0] + 8.f) || (mx[1] > mrun[1] + 8.f) ||
                  (mx[2] > mrun[2] + 8.f) || (mx[3] > mrun[3] + 8.f);
      if (__any(grow)) {
        float resc[4];
        #pragma unroll
        for (int r = 0; r < 4; ++r) {
          float mnew = fmaxf(mrun[r], mx[r]);
          resc[r] = __expf(mrun[r] - mnew);
          mrun[r] = mnew;
          lrun[r] *= resc[r];
        }
        #pragma unroll
        for (int fd = 0; fd < 8; ++fd) {
          f32x4 a = acc[fd];
          a[0] *= resc[0]; a[1] *= resc[1]; a[2] *= resc[2]; a[3] *= resc[3];
          acc[fd] = a;
        }
      }
      #pragma unroll
      for (int r = 0; r < 4; ++r) {
        float sum = 0.f;
        #pragma unroll
        for (int f = 0; f < 4; ++f) {
          float e = __expf(p[f][r] - mrun[r]);
          p[f][r] = e;
          sum += e;
        }
        sum += __shfl_xor(sum, 1);
        sum += __shfl_xor(sum, 2);
        sum += __shfl_xor(sum, 4);
        sum += __shfl_xor(sum, 8);
        lrun[r] += sum;
      }
      // ---- P -> LDS (cvt_pk bf16, XOR-swizzled both sides), then PV ----
      {
        const int r0 = lg * 4;
        #pragma unroll
        for (int f = 0; f < 4; ++f) {
          const int col = f * 16 + lr;
          unsigned w01 = cvt_pk_bf16(p[f][0], p[f][1]);
          unsigned w23 = cvt_pk_bf16(p[f][2], p[f][3]);
          pw[(r0 + 0) * 64 + (col ^ (((r0 + 0) & 7) << 3))] = (u16)(w01 & 0xffffu);
          pw[(r0 + 1) * 64 + (col ^ (((r0 + 1) & 7) << 3))] = (u16)(w01 >> 16);
          pw[(r0 + 2) * 64 + (col ^ (((r0 + 2) & 7) << 3))] = (u16)(w23 & 0xffffu);
          pw[(r0 + 3) * 64 + (col ^ (((r0 + 3) & 7) << 3))] = (u16)(w23 >> 16);
        }
      }
      __builtin_amdgcn_s_setprio(1);
      #pragma unroll
      for (int ks = 0; ks < 2; ++ks) {
        int col0 = ks * 32 + lg * 8;
        bf16x8 pa = *(const bf16x8*)(pw + lr * 64 + (col0 ^ (swz << 3)));
        #pragma unroll
        for (int fd = 0; fd < 8; ++fd) {
          bf16x8 vb = *(const bf16x8*)(vl + (fd * 16 + lr) * 64 + (((ks * 4 + lg) ^ swz) * 8));
          acc[fd] = __builtin_amdgcn_mfma_f32_16x16x32_bf16(pa, vb, acc[fd], 0, 0, 0);
        }
      }
      __builtin_amdgcn_s_setprio(0);
      __syncthreads();               // next tile staged AND this buffer free
      cur ^= 1;
    }

    // ---- normalize + write bf16 [M][H] ----
    u16* ob = O + (size_t)(b * S + q0 + lg * 4) * H + h * HD;
    #pragma unroll
    for (int r = 0; r < 4; ++r) {
      float inv = 1.f / lrun[r];
      #pragma unroll
      for (int fd = 0; fd < 8; ++fd)
        ob[(size_t)r * H + fd * 16 + lr] = f2bf(acc[fd][r] * inv);
    }
  }
}

// ---------------- launch ----------------
extern "C" void kernel_launch(void* const* d_in, const int* in_sizes, int n_in,
                              void* d_out, int out_size, void* d_ws, size_t ws_size,
                              hipStream_t stream) {
  const float* x  = (const float*)d_in[0];
  const float* wq = (const float*)d_in[1];
  const float* bq = (const float*)d_in[2];
  const float* wk = (const float*)d_in[3];
  const float* bk = (const float*)d_in[4];
  const float* wv = (const float*)d_in[5];
  const float* bv = (const float*)d_in[6];
  const float* wo = (const float*)d_in[7];
  const float* bo = (const float*)d_in[8];

  char* ws = (char*)d_ws;
  u16*   xb  = (u16*)(ws);                       // 16 MiB  [M][H] bf16
  u16*   wqb = (u16*)(ws + (16ull << 20));       //  8 MiB
  u16*   wkb = (u16*)(ws + (24ull << 20));
  u16*   wvb = (u16*)(ws + (32ull << 20));
  u16*   wob = (u16*)(ws + (40ull << 20));
  u16*   Qb  = (u16*)(ws + (48ull << 20));       // 16 MiB
  u16*   Kb  = (u16*)(ws + (64ull << 20));       // 16 MiB
  u16*   Vt  = (u16*)(ws + (80ull << 20));       // 16 MiB [bh][d][s]
  u16*   Ob  = (u16*)(ws + (96ull << 20));       // 16 MiB
  float* tab = (float*)(ws + (112ull << 20));    //  1 MiB cos/sin

  cast_kernel<<<M * H / 1024, 256, 0, stream>>>(x, xb, M * H);
  cast4_kernel<<<dim3(H * H / 1024, 4), 256, 0, stream>>>(wq, wk, wv, wo, wqb, wkb, wvb, wob);
  rope_table_k<<<(S * 64 + 255) / 256, 256, 0, stream>>>(tab);

  gemm_qkv<<<dim3(H / 128, M / 128, 3), 256, 0, stream>>>(xb, wqb, wkb, wvb, bq, bk, bv, Qb, Kb, Vt);

  rope_apply2_k<<<dim3(M * NH * 8 / 256, 2), 256, 0, stream>>>(Qb, Kb, tab);

  attn_fwd<<<dim3(512), 256, 0, stream>>>(Qb, Kb, Vt, Ob);

  gemm_out<<<dim3(H / 128, M / 128), 256, 0, stream>>>(Ob, wob, bo, (float*)d_out);
}